// Round 3
// baseline (93.341 us; speedup 1.0000x reference)
//
#include <hip/hip_runtime.h>

#define NFEAT   100000
#define NBATCH  256
#define DIM     128
#define MARGIN_F 0.5f
#define BN      64                        // feature cols per block
#define NBLK    ((NFEAT + BN - 1) / BN)   // 1563
#define FLT_BIG 3.402823466e+38f

typedef __bf16 bf8_t  __attribute__((ext_vector_type(8)));
typedef short  sh8_t  __attribute__((ext_vector_type(8)));
typedef float  f32x4  __attribute__((ext_vector_type(4)));

// f32 -> bf16 via native cast: compiler emits v_cvt_pk_bf16_f32 pairs (RTNE).
__device__ __forceinline__ bf8_t pack8(float4 v0, float4 v1) {
  bf8_t r;
  r[0] = (__bf16)v0.x; r[1] = (__bf16)v0.y; r[2] = (__bf16)v0.z; r[3] = (__bf16)v0.w;
  r[4] = (__bf16)v1.x; r[5] = (__bf16)v1.y; r[6] = (__bf16)v1.z; r[7] = (__bf16)v1.w;
  return r;
}

// MFMA dispatch: works whether the builtin takes bf16-vectors or short-vectors
template <typename VA, typename VC>
__device__ __forceinline__ auto mfma_sel(VA a, VA b, VC c, int)
    -> decltype(__builtin_amdgcn_mfma_f32_16x16x32_bf16(a, b, c, 0, 0, 0)) {
  return __builtin_amdgcn_mfma_f32_16x16x32_bf16(a, b, c, 0, 0, 0);
}
template <typename VA, typename VC>
__device__ __forceinline__ VC mfma_sel(VA a, VA b, VC c, long) {
  return __builtin_amdgcn_mfma_f32_16x16x32_bf16(
      __builtin_bit_cast(sh8_t, a), __builtin_bit_cast(sh8_t, b), c, 0, 0, 0);
}
__device__ __forceinline__ f32x4 mfma_bf16(bf8_t a, bf8_t b, f32x4 c) {
  return mfma_sel(a, b, c, 0);
}

// Kernel 1: fused GEMM + masked min/max partial reduction.
// Block b: feature cols [b*64, b*64+64). 8 waves; wave w owns batch rows
// [32w, 32w+32) (2 M-tiles of 16). B prefetched one ng-group (16 cols) ahead
// in registers; inline f32->bf16; MFMA 16x16x32 (layouts per guide §3):
//   A: lane l holds A[m0 + (l&15)][k0 + (l>>4)*8 + e]
//   B: lane l holds B[k0 + (l>>4)*8 + e][j0 + (l&15)]   (= features[j][k])
//   D: lane l reg r = sim[m0 + (l>>4)*4 + r][j0 + (l&15)]
__global__ __launch_bounds__(512) void triplet_partial(
    const float* __restrict__ inputs, const float* __restrict__ features,
    const int* __restrict__ targets, const int* __restrict__ flabels,
    const int* __restrict__ idx,
    float* __restrict__ ppos, float* __restrict__ pneg,
    float* __restrict__ out)
{
  const int tid  = threadIdx.x;
  const int lane = tid & 63;
  const int wv   = tid >> 6;      // 0..7
  const int l15  = lane & 15;
  const int lg   = lane >> 4;     // 0..3
  const int m0   = wv * 32;
  const int blk  = blockIdx.x;
  const int jbase = blk * BN;

  if (blk == 0 && tid == 0) out[0] = 0.0f;   // kernel 2 accumulates atomically

  // A fragments: [2 M-tiles][4 K-steps]
  bf8_t afrag[2][4];
#pragma unroll
  for (int mt = 0; mt < 2; ++mt) {
    const float* ap = inputs + (m0 + mt * 16 + l15) * DIM;
#pragma unroll
    for (int ks = 0; ks < 4; ++ks) {
      const int k = ks * 32 + lg * 8;
      float4 v0 = *reinterpret_cast<const float4*>(ap + k);
      float4 v1 = *reinterpret_cast<const float4*>(ap + k + 4);
      afrag[mt][ks] = pack8(v0, v1);
    }
  }

  // Row metadata for the 8 output rows this lane sees
  int tgt[2][4], sidx[2][4];
#pragma unroll
  for (int mt = 0; mt < 2; ++mt)
#pragma unroll
    for (int rr = 0; rr < 4; ++rr) {
      const int row = m0 + mt * 16 + lg * 4 + rr;
      tgt[mt][rr]  = targets[row];
      sidx[mt][rr] = idx[row];
    }

  float minpos[2][4], maxneg[2][4];
#pragma unroll
  for (int mt = 0; mt < 2; ++mt)
#pragma unroll
    for (int rr = 0; rr < 4; ++rr) { minpos[mt][rr] = FLT_BIG; maxneg[mt][rr] = -FLT_BIG; }

  // --- software-pipelined B: prefetch ng=0
  float4 nx[8];
  int labn;
  {
    const int j0 = jbase + l15;
    const int jc = (j0 < NFEAT) ? j0 : (NFEAT - 1);
    const float* fp = features + (long)jc * DIM;
#pragma unroll
    for (int ks = 0; ks < 4; ++ks) {
      const int k = ks * 32 + lg * 8;
      nx[2 * ks]     = *reinterpret_cast<const float4*>(fp + k);
      nx[2 * ks + 1] = *reinterpret_cast<const float4*>(fp + k + 4);
    }
    labn = flabels[jc];
  }

#pragma unroll
  for (int ng = 0; ng < BN / 16; ++ng) {
    // convert current B tile (loads for it were issued last iteration)
    bf8_t bfrag[4];
#pragma unroll
    for (int ks = 0; ks < 4; ++ks)
      bfrag[ks] = pack8(nx[2 * ks], nx[2 * ks + 1]);
    const int  j      = jbase + ng * 16 + l15;
    const bool jvalid = (j < NFEAT);
    const int  labj   = labn;

    // issue next tile's loads; they land under the MFMAs + epilogue below
    if (ng < BN / 16 - 1) {
      const int jn = jbase + (ng + 1) * 16 + l15;
      const int jc = (jn < NFEAT) ? jn : (NFEAT - 1);
      const float* fp = features + (long)jc * DIM;
#pragma unroll
      for (int ks = 0; ks < 4; ++ks) {
        const int k = ks * 32 + lg * 8;
        nx[2 * ks]     = *reinterpret_cast<const float4*>(fp + k);
        nx[2 * ks + 1] = *reinterpret_cast<const float4*>(fp + k + 4);
      }
      labn = flabels[jc];
    }

#pragma unroll
    for (int mt = 0; mt < 2; ++mt) {
      f32x4 acc = {0.f, 0.f, 0.f, 0.f};
#pragma unroll
      for (int ks = 0; ks < 4; ++ks)
        acc = mfma_bf16(afrag[mt][ks], bfrag[ks], acc);
#pragma unroll
      for (int rr = 0; rr < 4; ++rr) {
        const float s    = acc[rr];
        const bool same  = (labj == tgt[mt][rr]);
        const bool posok = jvalid && same && (j != sidx[mt][rr]);
        const bool negok = jvalid && !same;
        minpos[mt][rr] = fminf(minpos[mt][rr], posok ? s :  FLT_BIG);
        maxneg[mt][rr] = fmaxf(maxneg[mt][rr], negok ? s : -FLT_BIG);
      }
    }
  }

  // Reduce over the 16 cols held across each 16-lane group; coalesced write
#pragma unroll
  for (int mt = 0; mt < 2; ++mt)
#pragma unroll
    for (int rr = 0; rr < 4; ++rr) {
      float mp = minpos[mt][rr], mn = maxneg[mt][rr];
#pragma unroll
      for (int m = 1; m < 16; m <<= 1) {
        mp = fminf(mp, __shfl_xor(mp, m, 64));
        mn = fmaxf(mn, __shfl_xor(mn, m, 64));
      }
      if (l15 == 0) {
        const int row = m0 + mt * 16 + lg * 4 + rr;
        ppos[blk * NBATCH + row] = mp;   // [blk][row]: contiguous per block
        pneg[blk * NBATCH + row] = mn;
      }
    }
}

// Kernel 2: one block per batch row; fold NBLK partials (L2-resident), hinge,
// atomic mean-accumulate into out[0].
__global__ __launch_bounds__(256) void triplet_reduce(
    const float* __restrict__ ppos, const float* __restrict__ pneg,
    float* __restrict__ out)
{
  const int r = blockIdx.x;
  const int t = threadIdx.x;
  float mp = FLT_BIG, mn = -FLT_BIG;
  for (int b = t; b < NBLK; b += 256) {
    mp = fminf(mp, ppos[b * NBATCH + r]);
    mn = fmaxf(mn, pneg[b * NBATCH + r]);
  }
#pragma unroll
  for (int m = 1; m < 64; m <<= 1) {
    mp = fminf(mp, __shfl_xor(mp, m, 64));
    mn = fmaxf(mn, __shfl_xor(mn, m, 64));
  }
  __shared__ float smp[4], smn[4];
  if ((t & 63) == 0) { smp[t >> 6] = mp; smn[t >> 6] = mn; }
  __syncthreads();
  if (t == 0) {
    mp = fminf(fminf(smp[0], smp[1]), fminf(smp[2], smp[3]));
    mn = fmaxf(fmaxf(smn[0], smn[1]), fmaxf(smn[2], smn[3]));
    float loss = mn - mp + MARGIN_F;
    loss = loss > 0.f ? loss : 0.f;
    atomicAdd(out, loss * (1.0f / NBATCH));
  }
}

extern "C" void kernel_launch(void* const* d_in, const int* in_sizes, int n_in,
                              void* d_out, int out_size, void* d_ws, size_t ws_size,
                              hipStream_t stream) {
  const float* inputs   = (const float*)d_in[0];
  const float* features = (const float*)d_in[1];
  const int*   targets  = (const int*)d_in[2];
  const int*   flabels  = (const int*)d_in[3];
  const int*   idx      = (const int*)d_in[4];
  float* out  = (float*)d_out;
  float* ppos = (float*)d_ws;                 // [NBLK][256]
  float* pneg = ppos + (size_t)NBLK * NBATCH; // [NBLK][256]  (~3.2 MB total)

  triplet_partial<<<NBLK, 512, 0, stream>>>(inputs, features, targets, flabels, idx, ppos, pneg, out);
  triplet_reduce<<<NBATCH, 256, 0, stream>>>(ppos, pneg, out);
}

// Round 4
// 81.079 us; speedup vs baseline: 1.1512x; 1.1512x over previous
//
#include <hip/hip_runtime.h>

#define NFEAT   100000
#define NBATCH  256
#define DIM     128
#define MARGIN_F 0.5f
#define BN      128                       // feature cols (rows of `features`) per block
#define NBLK    ((NFEAT + BN - 1) / BN)   // 782
#define CROWS   32                        // feature rows per staged chunk
#define NCHUNK  (BN / CROWS)              // 4
#define CBYTES  (CROWS * DIM * 4)         // 16 KiB per chunk buffer
#define FLT_BIG 3.402823466e+38f

typedef __bf16 bf8_t  __attribute__((ext_vector_type(8)));
typedef short  sh8_t  __attribute__((ext_vector_type(8)));
typedef float  f32x4  __attribute__((ext_vector_type(4)));

// f32 -> bf16 via native cast: compiler emits v_cvt_pk_bf16_f32 pairs (RTNE).
__device__ __forceinline__ bf8_t pack8(float4 v0, float4 v1) {
  bf8_t r;
  r[0] = (__bf16)v0.x; r[1] = (__bf16)v0.y; r[2] = (__bf16)v0.z; r[3] = (__bf16)v0.w;
  r[4] = (__bf16)v1.x; r[5] = (__bf16)v1.y; r[6] = (__bf16)v1.z; r[7] = (__bf16)v1.w;
  return r;
}

// MFMA dispatch: works whether the builtin takes bf16-vectors or short-vectors
template <typename VA, typename VC>
__device__ __forceinline__ auto mfma_sel(VA a, VA b, VC c, int)
    -> decltype(__builtin_amdgcn_mfma_f32_16x16x32_bf16(a, b, c, 0, 0, 0)) {
  return __builtin_amdgcn_mfma_f32_16x16x32_bf16(a, b, c, 0, 0, 0);
}
template <typename VA, typename VC>
__device__ __forceinline__ VC mfma_sel(VA a, VA b, VC c, long) {
  return __builtin_amdgcn_mfma_f32_16x16x32_bf16(
      __builtin_bit_cast(sh8_t, a), __builtin_bit_cast(sh8_t, b), c, 0, 0, 0);
}
__device__ __forceinline__ f32x4 mfma_bf16(bf8_t a, bf8_t b, f32x4 c) {
  return mfma_sel(a, b, c, 0);
}

#if defined(__has_builtin)
#if __has_builtin(__builtin_amdgcn_global_load_lds)
#define HAVE_GLLDS 1
#endif
#endif

// 16B global -> LDS. Async DMA when available (no VGPR round-trip).
__device__ __forceinline__ void stage16(const char* g, char* l) {
#ifdef HAVE_GLLDS
  __builtin_amdgcn_global_load_lds(
      (const __attribute__((address_space(1))) unsigned int*)g,
      (__attribute__((address_space(3))) unsigned int*)l, 16, 0, 0);
#else
  *reinterpret_cast<float4*>(l) = *reinterpret_cast<const float4*>(g);
#endif
}

// Kernel 1: fused GEMM + masked min/max partial reduction.
// Block b: feature cols [b*128, b*128+128), staged as 4 chunks of 32 rows into
// double-buffered LDS via global_load_lds (T3 2-phase). 4 waves; wave w owns
// batch rows [64w, 64w+64) (4 M-tiles of 16). B tiles XOR-swizzled
// (byte ^= (row&7)<<4) via pre-swizzled GLOBAL source (linear LDS dest, rule 21)
// so ds_read_b128 B-frag reads are conflict-minimal.
// MFMA 16x16x32 layouts (guide §3, m89/m91-verified):
//   A: lane l holds A[m0 + (l&15)][k0 + (l>>4)*8 + e]
//   B: lane l holds B[k0 + (l>>4)*8 + e][j0 + (l&15)]   (= features[j][k])
//   D: lane l reg r = sim[m0 + (l>>4)*4 + r][j0 + (l&15)]
__global__ __launch_bounds__(256) void triplet_partial(
    const float* __restrict__ inputs, const float* __restrict__ features,
    const int* __restrict__ targets, const int* __restrict__ flabels,
    const int* __restrict__ idx,
    float* __restrict__ ppos, float* __restrict__ pneg,
    float* __restrict__ out)
{
  __shared__ char sbuf[2][CBYTES];   // 32 KiB
  __shared__ int  slab[BN];          // labels for this block's 128 cols

  const int tid  = threadIdx.x;
  const int lane = tid & 63;
  const int wv   = tid >> 6;      // 0..3
  const int l15  = lane & 15;
  const int lg   = lane >> 4;     // 0..3
  const int m0   = wv * 64;
  const int blk  = blockIdx.x;
  const int jbase = blk * BN;

  if (blk == 0 && tid == 0) out[0] = 0.0f;   // kernel 2 accumulates atomically

  // ---- async-stage one 32-row chunk: 4 x 16B per thread, linear LDS dest,
  //      pre-swizzled global source (inverse of the read-side XOR).
  auto stage_chunk = [&](int buf, int c) {
    const int rowbase = jbase + c * CROWS;
#pragma unroll
    for (int i = 0; i < 4; ++i) {
      const int p    = i * 4096 + tid * 16;         // LDS byte (uniform + lane*16)
      const int prow = p >> 9;                      // 0..31
      int srow = rowbase + prow;
      srow = srow < NFEAT ? srow : NFEAT - 1;       // clamp OOB (masked later)
      const int scol = (p & 511) ^ ((prow & 7) << 4);
      stage16((const char*)features + (size_t)srow * 512 + scol, &sbuf[buf][p]);
    }
  };

  stage_chunk(0, 0);   // prefetch chunk 0; lands under the A-prologue below

  // labels for this block's cols -> LDS
  if (tid < BN) {
    int jc = jbase + tid; jc = jc < NFEAT ? jc : NFEAT - 1;
    slab[tid] = flabels[jc];
  }

  // A fragments [4 M-tiles][4 K-steps] in VGPRs
  bf8_t afrag[4][4];
#pragma unroll
  for (int mt = 0; mt < 4; ++mt) {
    const float* ap = inputs + (m0 + mt * 16 + l15) * DIM;
#pragma unroll
    for (int ks = 0; ks < 4; ++ks) {
      const int k = ks * 32 + lg * 8;
      float4 v0 = *reinterpret_cast<const float4*>(ap + k);
      float4 v1 = *reinterpret_cast<const float4*>(ap + k + 4);
      afrag[mt][ks] = pack8(v0, v1);
    }
  }

  // packed row metadata: meta = (self_gallery_row << 16) | target_label
  int meta[4][4];
#pragma unroll
  for (int mt = 0; mt < 4; ++mt)
#pragma unroll
    for (int rr = 0; rr < 4; ++rr) {
      const int row = m0 + mt * 16 + lg * 4 + rr;
      meta[mt][rr] = (idx[row] << 16) | targets[row];
    }

  float minpos[4][4], maxneg[4][4];
#pragma unroll
  for (int mt = 0; mt < 4; ++mt)
#pragma unroll
    for (int rr = 0; rr < 4; ++rr) { minpos[mt][rr] = FLT_BIG; maxneg[mt][rr] = -FLT_BIG; }

  __syncthreads();   // chunk 0 staged (vmcnt0) + labels visible (lgkm0)

#pragma unroll
  for (int c = 0; c < NCHUNK; ++c) {
    const int cur = c & 1;
    if (c + 1 < NCHUNK) stage_chunk(cur ^ 1, c + 1);  // async; overlaps compute

#pragma unroll
    for (int g = 0; g < CROWS / 16; ++g) {            // 2 col-groups of 16
      const int  j      = jbase + c * CROWS + g * 16 + l15;
      const bool jvalid = (j < NFEAT);
      const int  labj   = slab[c * CROWS + g * 16 + l15];

      // B frags from swizzled LDS
      bf8_t bfrag[4];
      const char* rbase = &sbuf[cur][(g * 16 + l15) * 512];
      const int   swz   = (l15 & 7) << 4;
#pragma unroll
      for (int ks = 0; ks < 4; ++ks) {
        const int b0 = ks * 128 + lg * 32;
        float4 v0 = *reinterpret_cast<const float4*>(rbase + ((b0)      ^ swz));
        float4 v1 = *reinterpret_cast<const float4*>(rbase + ((b0 + 16) ^ swz));
        bfrag[ks] = pack8(v0, v1);
      }

#pragma unroll
      for (int mt = 0; mt < 4; ++mt) {
        f32x4 acc = {0.f, 0.f, 0.f, 0.f};
#pragma unroll
        for (int ks = 0; ks < 4; ++ks)
          acc = mfma_bf16(afrag[mt][ks], bfrag[ks], acc);
#pragma unroll
        for (int rr = 0; rr < 4; ++rr) {
          const float s    = acc[rr];
          const int   m    = meta[mt][rr];
          const bool same  = (labj == (m & 0xffff));
          const bool posok = jvalid && same && (j != (m >> 16));
          const bool negok = jvalid && !same;
          minpos[mt][rr] = fminf(minpos[mt][rr], posok ? s :  FLT_BIG);
          maxneg[mt][rr] = fmaxf(maxneg[mt][rr], negok ? s : -FLT_BIG);
        }
      }
    }
    __syncthreads();  // drains vmcnt(0): next chunk staged; safe to swap buffers
  }

  // Reduce over the 16 cols held across each 16-lane group; coalesced write
#pragma unroll
  for (int mt = 0; mt < 4; ++mt)
#pragma unroll
    for (int rr = 0; rr < 4; ++rr) {
      float mp = minpos[mt][rr], mn = maxneg[mt][rr];
#pragma unroll
      for (int m = 1; m < 16; m <<= 1) {
        mp = fminf(mp, __shfl_xor(mp, m, 64));
        mn = fmaxf(mn, __shfl_xor(mn, m, 64));
      }
      if (l15 == 0) {
        const int row = m0 + mt * 16 + lg * 4 + rr;
        ppos[blk * NBATCH + row] = mp;   // [blk][row]: contiguous per block
        pneg[blk * NBATCH + row] = mn;
      }
    }
}

// Kernel 2: one block per batch row; fold NBLK partials (L2-resident), hinge,
// atomic mean-accumulate into out[0].
__global__ __launch_bounds__(256) void triplet_reduce(
    const float* __restrict__ ppos, const float* __restrict__ pneg,
    float* __restrict__ out)
{
  const int r = blockIdx.x;
  const int t = threadIdx.x;
  float mp = FLT_BIG, mn = -FLT_BIG;
  for (int b = t; b < NBLK; b += 256) {
    mp = fminf(mp, ppos[b * NBATCH + r]);
    mn = fmaxf(mn, pneg[b * NBATCH + r]);
  }
#pragma unroll
  for (int m = 1; m < 64; m <<= 1) {
    mp = fminf(mp, __shfl_xor(mp, m, 64));
    mn = fmaxf(mn, __shfl_xor(mn, m, 64));
  }
  __shared__ float smp[4], smn[4];
  if ((t & 63) == 0) { smp[t >> 6] = mp; smn[t >> 6] = mn; }
  __syncthreads();
  if (t == 0) {
    mp = fminf(fminf(smp[0], smp[1]), fminf(smp[2], smp[3]));
    mn = fmaxf(fmaxf(smn[0], smn[1]), fmaxf(smn[2], smn[3]));
    float loss = mn - mp + MARGIN_F;
    loss = loss > 0.f ? loss : 0.f;
    atomicAdd(out, loss * (1.0f / NBATCH));
  }
}

extern "C" void kernel_launch(void* const* d_in, const int* in_sizes, int n_in,
                              void* d_out, int out_size, void* d_ws, size_t ws_size,
                              hipStream_t stream) {
  const float* inputs   = (const float*)d_in[0];
  const float* features = (const float*)d_in[1];
  const int*   targets  = (const int*)d_in[2];
  const int*   flabels  = (const int*)d_in[3];
  const int*   idx      = (const int*)d_in[4];
  float* out  = (float*)d_out;
  float* ppos = (float*)d_ws;                 // [NBLK][256]
  float* pneg = ppos + (size_t)NBLK * NBATCH; // [NBLK][256]  (~1.6 MB total)

  triplet_partial<<<NBLK, 256, 0, stream>>>(inputs, features, targets, flabels, idx, ppos, pneg, out);
  triplet_reduce<<<NBATCH, 256, 0, stream>>>(ppos, pneg, out);
}

// Round 5
// 49.191 us; speedup vs baseline: 1.8975x; 1.6482x over previous
//
#include <hip/hip_runtime.h>

#define NFEAT   100000
#define NBATCH  256
#define DIM     128
#define MARGIN_F 0.5f
#define BN      128                       // feature rows per block
#define NBLK    ((NFEAT + BN - 1) / BN)   // 782
#define CROWS   16                        // feature rows per staged chunk
#define NCHUNK  (BN / CROWS)              // 8
#define NBUF    4                         // pipeline depth (LDS buffers)
#define CBYTES  (CROWS * DIM * 4)         // 8 KiB per chunk
#define FLT_BIG 3.402823466e+38f

typedef __bf16 bf8_t  __attribute__((ext_vector_type(8)));
typedef short  sh8_t  __attribute__((ext_vector_type(8)));
typedef float  f32x4  __attribute__((ext_vector_type(4)));

// f32 -> bf16 native cast: compiler emits v_cvt_pk_bf16_f32 pairs (RTNE).
__device__ __forceinline__ bf8_t pack8(float4 v0, float4 v1) {
  bf8_t r;
  r[0] = (__bf16)v0.x; r[1] = (__bf16)v0.y; r[2] = (__bf16)v0.z; r[3] = (__bf16)v0.w;
  r[4] = (__bf16)v1.x; r[5] = (__bf16)v1.y; r[6] = (__bf16)v1.z; r[7] = (__bf16)v1.w;
  return r;
}

// MFMA dispatch: works whether the builtin takes bf16-vectors or short-vectors
template <typename VA, typename VC>
__device__ __forceinline__ auto mfma_sel(VA a, VA b, VC c, int)
    -> decltype(__builtin_amdgcn_mfma_f32_16x16x32_bf16(a, b, c, 0, 0, 0)) {
  return __builtin_amdgcn_mfma_f32_16x16x32_bf16(a, b, c, 0, 0, 0);
}
template <typename VA, typename VC>
__device__ __forceinline__ VC mfma_sel(VA a, VA b, VC c, long) {
  return __builtin_amdgcn_mfma_f32_16x16x32_bf16(
      __builtin_bit_cast(sh8_t, a), __builtin_bit_cast(sh8_t, b), c, 0, 0, 0);
}
__device__ __forceinline__ f32x4 mfma_bf16(bf8_t a, bf8_t b, f32x4 c) {
  return mfma_sel(a, b, c, 0);
}

#if defined(__has_builtin)
#if __has_builtin(__builtin_amdgcn_global_load_lds)
#define HAVE_GLLDS 1
#endif
#endif

// 16B global -> LDS async DMA (no VGPR round-trip; counted by vmcnt).
__device__ __forceinline__ void stage16(const char* g, char* l) {
#ifdef HAVE_GLLDS
  __builtin_amdgcn_global_load_lds(
      (const __attribute__((address_space(1))) unsigned int*)g,
      (__attribute__((address_space(3))) unsigned int*)l, 16, 0, 0);
#else
  *reinterpret_cast<float4*>(l) = *reinterpret_cast<const float4*>(g);
#endif
}

#define WAITVM(N) asm volatile("s_waitcnt vmcnt(" #N ")" ::: "memory")
#define CFENCE()  asm volatile("" ::: "memory")

// Kernel 1: fused GEMM + masked min/max partial reduction, counted-vmcnt
// software pipeline (T4): 4 LDS chunk buffers, loads stay in flight across
// barriers (vmcnt never drained to 0 in the main loop).
// Block b: feature rows [b*128, b*128+128) in 8 chunks of 16. 8 waves; wave w
// owns batch rows [32w, 32w+32) (2 M-tiles). A-frags in VGPRs. B staged f32
// via global_load_lds with pre-swizzled source (linear LDS dest, rule 21);
// reads undo the XOR (byte ^= (row&7)<<4) -> measured-negligible conflicts.
// MFMA 16x16x32 layouts (guide §3, m89/m91-verified):
//   A: lane l holds A[m0 + (l&15)][k0 + (l>>4)*8 + e]
//   B: lane l holds B[k0 + (l>>4)*8 + e][j0 + (l&15)]   (= features[j][k])
//   D: lane l reg r = sim[m0 + (l>>4)*4 + r][j0 + (l&15)]
__global__ __launch_bounds__(512, 4) void triplet_partial(
    const float* __restrict__ inputs, const float* __restrict__ features,
    const int* __restrict__ targets, const int* __restrict__ flabels,
    const int* __restrict__ idx,
    float* __restrict__ ppos, float* __restrict__ pneg,
    float* __restrict__ out)
{
  __shared__ char sbuf[NBUF][CBYTES];   // 32 KiB
  __shared__ int  slab[BN];             // labels for this block's 128 rows

  const int tid  = threadIdx.x;
  const int lane = tid & 63;
  const int wv   = tid >> 6;      // 0..7
  const int l15  = lane & 15;
  const int lg   = lane >> 4;     // 0..3
  const int m0   = wv * 32;
  const int blk  = blockIdx.x;
  const int jbase = blk * BN;

  // stage one 16-row chunk: 1 x 16B per thread, linear LDS dest,
  // pre-swizzled global source (inverse of the read-side XOR).
  auto stage_chunk = [&](int buf, int c) {
    const int p    = tid * 16;                    // LDS byte within chunk
    const int prow = p >> 9;                      // 0..15
    int srow = jbase + c * CROWS + prow;
    srow = srow < NFEAT ? srow : NFEAT - 1;       // clamp OOB (masked later)
    const int scol = (p & 511) ^ ((prow & 7) << 4);
    stage16((const char*)features + (size_t)srow * 512 + scol, &sbuf[buf][p]);
  };

  // ---- prologue: issue A + metadata loads FIRST (their compiler waitcnts
  // then leave the later-issued stage DMAs in flight), then stages c0..c2.
  float4 av0[2][4], av1[2][4];
#pragma unroll
  for (int mt = 0; mt < 2; ++mt) {
    const float* ap = inputs + (m0 + mt * 16 + l15) * DIM;
#pragma unroll
    for (int ks = 0; ks < 4; ++ks) {
      const int k = ks * 32 + lg * 8;
      av0[mt][ks] = *reinterpret_cast<const float4*>(ap + k);
      av1[mt][ks] = *reinterpret_cast<const float4*>(ap + k + 4);
    }
  }
  int tgt[2][4], sid[2][4];
#pragma unroll
  for (int mt = 0; mt < 2; ++mt)
#pragma unroll
    for (int rr = 0; rr < 4; ++rr) {
      const int row = m0 + mt * 16 + lg * 4 + rr;
      tgt[mt][rr] = targets[row];
      sid[mt][rr] = idx[row];
    }

  stage_chunk(0, 0); stage_chunk(1, 1); stage_chunk(2, 2);

  if (blk == 0 && tid == 0) out[0] = 0.0f;   // kernel 2 accumulates atomically

  // convert A (consumes av*: compiler waits only to that depth)
  bf8_t afrag[2][4];
#pragma unroll
  for (int mt = 0; mt < 2; ++mt)
#pragma unroll
    for (int ks = 0; ks < 4; ++ks)
      afrag[mt][ks] = pack8(av0[mt][ks], av1[mt][ks]);

  if (tid < BN) {
    int jc = jbase + tid; jc = jc < NFEAT ? jc : NFEAT - 1;
    slab[tid] = flabels[jc];
  }

  float minpos[2][4], maxneg[2][4];
#pragma unroll
  for (int mt = 0; mt < 2; ++mt)
#pragma unroll
    for (int rr = 0; rr < 4; ++rr) { minpos[mt][rr] = FLT_BIG; maxneg[mt][rr] = -FLT_BIG; }

  asm volatile("s_waitcnt lgkmcnt(0)" ::: "memory");  // slab visible
  __builtin_amdgcn_s_barrier();
  CFENCE();

  // ---- main loop: wait(counted) -> barrier -> issue c+3 -> compute c
#pragma unroll
  for (int c = 0; c < NCHUNK; ++c) {
    // chunk c landed (this wave); outstanding = min(3, NCHUNK-c) chunks
    if (c < NCHUNK - 2)      { WAITVM(2); }
    else if (c == NCHUNK - 2){ WAITVM(1); }
    else                     { WAITVM(0); }
    __builtin_amdgcn_s_barrier();   // all waves' chunk-c slices in LDS;
    CFENCE();                       // all waves done computing chunk c-1

    if (c + 3 < NCHUNK) stage_chunk((c + 3) & 3, c + 3);  // overwrite buf (c-1)

    const int  jcol   = c * CROWS + l15;
    const int  j      = jbase + jcol;
    const bool jvalid = (j < NFEAT);
    const int  labj   = slab[jcol];

    // B frags from swizzled LDS
    bf8_t bfrag[4];
    const char* rbase = &sbuf[c & 3][l15 * 512];
    const int   swz   = (l15 & 7) << 4;
#pragma unroll
    for (int ks = 0; ks < 4; ++ks) {
      const int b0 = ks * 128 + lg * 32;
      float4 v0 = *reinterpret_cast<const float4*>(rbase + ((b0)      ^ swz));
      float4 v1 = *reinterpret_cast<const float4*>(rbase + ((b0 + 16) ^ swz));
      bfrag[ks] = pack8(v0, v1);
    }

#pragma unroll
    for (int mt = 0; mt < 2; ++mt) {
      f32x4 acc = {0.f, 0.f, 0.f, 0.f};
#pragma unroll
      for (int ks = 0; ks < 4; ++ks)
        acc = mfma_bf16(afrag[mt][ks], bfrag[ks], acc);
#pragma unroll
      for (int rr = 0; rr < 4; ++rr) {
        const float s    = acc[rr];
        const bool same  = (labj == tgt[mt][rr]);
        const bool posok = jvalid && same && (j != sid[mt][rr]);
        const bool negok = jvalid && !same;
        minpos[mt][rr] = fminf(minpos[mt][rr], posok ? s :  FLT_BIG);
        maxneg[mt][rr] = fmaxf(maxneg[mt][rr], negok ? s : -FLT_BIG);
      }
    }
  }

  // Reduce over the 16 cols held across each 16-lane group; coalesced write
#pragma unroll
  for (int mt = 0; mt < 2; ++mt)
#pragma unroll
    for (int rr = 0; rr < 4; ++rr) {
      float mp = minpos[mt][rr], mn = maxneg[mt][rr];
#pragma unroll
      for (int m = 1; m < 16; m <<= 1) {
        mp = fminf(mp, __shfl_xor(mp, m, 64));
        mn = fmaxf(mn, __shfl_xor(mn, m, 64));
      }
      if (l15 == 0) {
        const int row = m0 + mt * 16 + lg * 4 + rr;
        ppos[blk * NBATCH + row] = mp;   // [blk][row]: contiguous per block
        pneg[blk * NBATCH + row] = mn;
      }
    }
}

// Kernel 2: one block per batch row; fold NBLK partials (L2-resident), hinge,
// atomic mean-accumulate into out[0].
__global__ __launch_bounds__(256) void triplet_reduce(
    const float* __restrict__ ppos, const float* __restrict__ pneg,
    float* __restrict__ out)
{
  const int r = blockIdx.x;
  const int t = threadIdx.x;
  float mp = FLT_BIG, mn = -FLT_BIG;
  for (int b = t; b < NBLK; b += 256) {
    mp = fminf(mp, ppos[b * NBATCH + r]);
    mn = fmaxf(mn, pneg[b * NBATCH + r]);
  }
#pragma unroll
  for (int m = 1; m < 64; m <<= 1) {
    mp = fminf(mp, __shfl_xor(mp, m, 64));
    mn = fmaxf(mn, __shfl_xor(mn, m, 64));
  }
  __shared__ float smp[4], smn[4];
  if ((t & 63) == 0) { smp[t >> 6] = mp; smn[t >> 6] = mn; }
  __syncthreads();
  if (t == 0) {
    mp = fminf(fminf(smp[0], smp[1]), fminf(smp[2], smp[3]));
    mn = fmaxf(fmaxf(smn[0], smn[1]), fmaxf(smn[2], smn[3]));
    float loss = mn - mp + MARGIN_F;
    loss = loss > 0.f ? loss : 0.f;
    atomicAdd(out, loss * (1.0f / NBATCH));
  }
}

extern "C" void kernel_launch(void* const* d_in, const int* in_sizes, int n_in,
                              void* d_out, int out_size, void* d_ws, size_t ws_size,
                              hipStream_t stream) {
  const float* inputs   = (const float*)d_in[0];
  const float* features = (const float*)d_in[1];
  const int*   targets  = (const int*)d_in[2];
  const int*   flabels  = (const int*)d_in[3];
  const int*   idx      = (const int*)d_in[4];
  float* out  = (float*)d_out;
  float* ppos = (float*)d_ws;                 // [NBLK][256]
  float* pneg = ppos + (size_t)NBLK * NBATCH; // [NBLK][256]  (~1.6 MB total)

  triplet_partial<<<NBLK, 512, 0, stream>>>(inputs, features, targets, flabels, idx, ppos, pneg, out);
  triplet_reduce<<<NBATCH, 256, 0, stream>>>(ppos, pneg, out);
}